// Round 1
// 560.817 us; speedup vs baseline: 1.0239x; 1.0239x over previous
//
#include <hip/hip_runtime.h>
#include <hip/hip_bf16.h>
#include <math.h>

#define N_PTS 16384
#define KNN 8

#define DT_BF16 1
#define DT_FP32 2

// Workspace layout:
//   flag : int          @ 0
//   idx  : int  [N*9]   @ 64        -> 589,824 B
//   x1   : f32  [N*64]  @ 589,888   -> 4,194,304 B
#define WS_FLAG_OFF 0
#define WS_IDX_OFF  64
#define WS_X1_OFF   589888
#define WS_NEEDED   4784192

__device__ __forceinline__ float bf2f(__hip_bfloat16 v) { return __bfloat162float(v); }

__device__ __forceinline__ float ldf(const float* p, int i) { return p[i]; }
__device__ __forceinline__ float ldf(const __hip_bfloat16* p, int i) { return bf2f(p[i]); }
__device__ __forceinline__ void stf(float* p, int i, float v) { p[i] = v; }
__device__ __forceinline__ void stf(__hip_bfloat16* p, int i, float v) { p[i] = __float2bfloat16(v); }

__device__ __forceinline__ int clamp_idx(int j) {
    return ((unsigned)j < (unsigned)N_PTS) ? j : 0;
}

// ---------------------------------------------------------------------------
// Kernel 0: dtype sniffer (unchanged; bf16 path confirmed by absmax).
// ---------------------------------------------------------------------------
__global__ __launch_bounds__(256) void sniff_kernel(const unsigned short* __restrict__ posu,
                                                    int* __restrict__ flag) {
    __shared__ int red[256];
    int local = 0;
    for (int e = threadIdx.x; e < 3 * N_PTS; e += 256) {
        const float v = __uint_as_float(((unsigned)posu[e]) << 16);
        if (!(fabsf(v) <= 64.0f)) local++;
    }
    red[threadIdx.x] = local;
    __syncthreads();
    for (int s = 128; s > 0; s >>= 1) {
        if (threadIdx.x < s) red[threadIdx.x] += red[threadIdx.x + s];
        __syncthreads();
    }
    if (threadIdx.x == 0) flag[0] = (red[0] > 16) ? DT_FP32 : DT_BF16;
}

// ---------------------------------------------------------------------------
// Kernel 1: brute-force KNN v3 — ONE TARGET PER WAVE.
// Rationale (r0 counters): v2 had 512 blocks -> 25% occupancy cap, and the
// insert-chain guard `if (d < tau)` fired at wave granularity ~95% of iters
// (8 targets x 8 scanners per wave = 64 uncorrelated predicates). v3 gives
// the whole 64-lane wave one target: tau is the wave-global 8th-best, so the
// insert branch fires only when a running-top-8 candidate appears (~15%).
// Grid 4096 blocks x 4 waves -> 8 blocks/CU (LDS 4KB, ~48 VGPR) -> full
// occupancy. Final merge: 64 per-lane sorted 8-lists k-way merged in-wave
// via shfl_xor lex-min butterflies (no LDS scratch, no serial phase).
// Distances stored as d' = d - |p_i|^2 (constant shift per target; ordering
// and tie behavior preserved).
// ---------------------------------------------------------------------------
template <bool CHECK_SELF>
__device__ __forceinline__ void scan4(const float4* __restrict__ spt, int base, int lane, int i,
                                      float pix, float piy, float piz,
                                      float (&bd)[KNN], int (&bi)[KNN], float& tau) {
#pragma unroll
    for (int m = 0; m < 4; ++m) {
        const int j = base + (m << 6) + lane;
        const float4 c = spt[(m << 6) + lane];
        float d = fmaf(c.x, pix, fmaf(c.y, piy, fmaf(c.z, piz, c.w)));
        if (CHECK_SELF && j == i) d = INFINITY;
        if (d < tau) {
            float cd = d; int ci = j;
#pragma unroll
            for (int q = 0; q < KNN; ++q) {
                const bool ins = cd < bd[q];
                const float nd = ins ? cd : bd[q];
                const int   ni = ins ? ci : bi[q];
                const float od = ins ? bd[q] : cd;
                const int   oi = ins ? bi[q] : ci;
                bd[q] = nd; bi[q] = ni; cd = od; ci = oi;
            }
            tau = fminf(tau, bd[KNN - 1]);   // own view tightens; still >= global 8th-best
        }
    }
}

template <typename T>
__global__ __launch_bounds__(256) void knn_kernel(const T* __restrict__ pos,
                                                  const int* __restrict__ flag, int want,
                                                  int* __restrict__ idx_out) {
    if (flag[0] != want) return;

    __shared__ float4 spt[256];

    const int tid  = threadIdx.x;
    const int wv   = tid >> 6;    // wave in block = target slot 0..3
    const int lane = tid & 63;
    const int i    = blockIdx.x * 4 + wv;

    const float pix = ldf(pos, 3 * i + 0);
    const float piy = ldf(pos, 3 * i + 1);
    const float piz = ldf(pos, 3 * i + 2);

    float bd[KNN];
    int   bi[KNN];
#pragma unroll
    for (int q = 0; q < KNN; ++q) { bd[q] = INFINITY; bi[q] = 0x7fffffff; }

    for (int base = 0; base < N_PTS; base += 256) {
        __syncthreads();   // previous tile fully consumed before restage
        {   // stage tile: (-2x, -2y, -2z, |p|^2)
            const int j = base + tid;
            const float x = ldf(pos, 3 * j + 0);
            const float y = ldf(pos, 3 * j + 1);
            const float z = ldf(pos, 3 * j + 2);
            const float sq = fmaf(x, x, fmaf(y, y, z * z));
            spt[tid] = make_float4(-2.0f * x, -2.0f * y, -2.0f * z, sq);
        }
        __syncthreads();

        // wave-shared tau: min over all 64 lanes' current 8th-best
        float tau = bd[KNN - 1];
#pragma unroll
        for (int s = 1; s < 64; s <<= 1) tau = fminf(tau, __shfl_xor(tau, s, 64));

        if ((unsigned)(i - base) < 256u)
            scan4<true >(spt, base, lane, i, pix, piy, piz, bd, bi, tau);
        else
            scan4<false>(spt, base, lane, i, pix, piy, piz, bd, bi, tau);
    }

    // In-wave k-way merge of 64 sorted 8-lists: 8 picks of the lex-min head.
    // Indices are unique across lanes (disjoint candidate subsets), so the
    // winning head identifies exactly one lane, which pops (shift-down).
#pragma unroll
    for (int k = 0; k < KNN; ++k) {
        float dw = bd[0];
        int   iw = bi[0];
#pragma unroll
        for (int s = 1; s < 64; s <<= 1) {
            const float od = __shfl_xor(dw, s, 64);
            const int   oi = __shfl_xor(iw, s, 64);
            if (od < dw || (od == dw && oi < iw)) { dw = od; iw = oi; }
        }
        if (bd[0] == dw && bi[0] == iw) {
#pragma unroll
            for (int q = 0; q < KNN - 1; ++q) { bd[q] = bd[q + 1]; bi[q] = bi[q + 1]; }
            bd[KNN - 1] = INFINITY; bi[KNN - 1] = 0x7fffffff;
        }
        if (lane == 0) idx_out[i * 9 + k] = clamp_idx(iw);
    }
    if (lane == 0) idx_out[i * 9 + 8] = i;
}

// ---------------------------------------------------------------------------
// Kernel 2: conv1 (unchanged).
// ---------------------------------------------------------------------------
template <typename T>
__global__ __launch_bounds__(256) void conv1_kernel(const T* __restrict__ pos,
                                                    const int* __restrict__ flag, int want,
                                                    const int* __restrict__ idx,
                                                    const T* __restrict__ W1a,
                                                    const T* __restrict__ b1a,
                                                    const T* __restrict__ W1b,
                                                    const T* __restrict__ b1b,
                                                    float* __restrict__ x1) {
    if (flag[0] != want) return;

    __shared__ float wA[6 * 32];
    __shared__ float bA[32];
    __shared__ float wB[32 * 64];
    __shared__ float bB[64];
    __shared__ float msg[4][9][6];
    __shared__ float h1s[4][9 * 32];

    const int tid = threadIdx.x;
    for (int e = tid; e < 192; e += 256) wA[e] = ldf(W1a, e);
    if (tid < 32) bA[tid] = ldf(b1a, tid);
    for (int e = tid; e < 2048; e += 256) wB[e] = ldf(W1b, e);
    if (tid < 64) bB[tid] = ldf(b1b, tid);

    const int tl   = tid >> 6;
    const int lane = tid & 63;
    const int i    = blockIdx.x * 4 + tl;

    if (lane < 54) {
        const int n = lane / 6, c = lane % 6;
        const int j = clamp_idx(idx[i * 9 + n]);
        float v = ldf(pos, 3 * j + (c % 3));
        if (c >= 3) v -= ldf(pos, 3 * i + (c - 3));
        msg[tl][n][c] = v;
    }
    __syncthreads();

    for (int e = lane; e < 288; e += 64) {
        const int n = e >> 5, k = e & 31;
        float s = bA[k];
#pragma unroll
        for (int c = 0; c < 6; ++c) s += msg[tl][n][c] * wA[c * 32 + k];
        h1s[tl][n * 32 + k] = fmaxf(s, 0.0f);
    }
    __syncthreads();

    float wcol[32];
#pragma unroll
    for (int k = 0; k < 32; ++k) wcol[k] = wB[k * 64 + lane];

    float acc = -INFINITY;
    for (int n = 0; n < 9; ++n) {
        float s = bB[lane];
#pragma unroll
        for (int k = 0; k < 32; ++k) s += h1s[tl][n * 32 + k] * wcol[k];
        acc = fmaxf(acc, s);
    }
    x1[i * 64 + lane] = fmaxf(acc, 0.0f);
}

// ---------------------------------------------------------------------------
// Kernel 3: conv2 + head (unchanged).
// ---------------------------------------------------------------------------
template <typename T>
__global__ __launch_bounds__(256) void conv2_head_kernel(const T* __restrict__ pos,
                                                         const int* __restrict__ flag, int want,
                                                         const int* __restrict__ idx,
                                                         const float* __restrict__ x1,
                                                         const T* __restrict__ W2a,
                                                         const T* __restrict__ b2a,
                                                         const T* __restrict__ W2b,
                                                         const T* __restrict__ b2b,
                                                         const T* __restrict__ Wc,
                                                         const T* __restrict__ bc,
                                                         T* __restrict__ out) {
    if (flag[0] != want) return;

    __shared__ float wAT[64 * 68];    // [k][c], c padded to 68, pad zeroed
    __shared__ float bA[64];
    __shared__ float wc[640];
    __shared__ float bcs[5];
    __shared__ float msg[4][9 * 68];  // [tgt][n*68+c], pad zeroed
    __shared__ float h1s[4][9 * 64];  // [tgt][n*64+k]
    __shared__ float row[4][128];
    __shared__ float sv[4][5];
    // ~41.4 KB LDS -> 3 blocks/CU

    const int tid  = threadIdx.x;
    const int l    = tid & 127;       // output channel for wB phase
    const int half = tid >> 7;        // 0/1 -> targets {0,1} / {2,3}

    // wB column + bias straight from global (coalesced, L2-resident)
    float wcol[64];
#pragma unroll
    for (int k = 0; k < 64; ++k) wcol[k] = ldf(W2b, k * 128 + l);
    const float bBl = ldf(b2b, l);

    // stage wA transposed; zero the pad column
    for (int e = tid; e < 4288; e += 256) {
        const int c = e >> 6, k = e & 63;
        wAT[k * 68 + c] = ldf(W2a, e);
    }
    if (tid < 64) wAT[tid * 68 + 67] = 0.0f;
    if (tid < 64) bA[tid] = ldf(b2a, tid);
    for (int e = tid; e < 640; e += 256) wc[e] = ldf(Wc, e);
    if (tid < 5) bcs[tid] = ldf(bc, tid);

    const int tl   = tid >> 6;        // target 0..3
    const int lane = tid & 63;
    const int i    = blockIdx.x * 4 + tl;

    // msg stage (+ zero pad)
    for (int e = lane; e < 603; e += 64) {
        const int n = e / 67, c = e % 67;
        const int j = clamp_idx(idx[i * 9 + n]);
        float v;
        if (c < 64) v = x1[j * 64 + c];
        else        v = ldf(pos, 3 * j + (c - 64)) - ldf(pos, 3 * i + (c - 64));
        msg[tl][n * 68 + c] = v;
    }
    if (lane < 9) msg[tl][lane * 68 + 67] = 0.0f;
    __syncthreads();

    // h1: thread = (target tl, channel lane); 9 accumulators over c
    {
        float h[9];
#pragma unroll
        for (int n = 0; n < 9; ++n) h[n] = bA[lane];
        for (int c = 0; c < 68; c += 4) {
            const float4 w = *(const float4*)&wAT[lane * 68 + c];
#pragma unroll
            for (int n = 0; n < 9; ++n) {
                const float4 mv = *(const float4*)&msg[tl][n * 68 + c];
                h[n] = fmaf(mv.x, w.x, h[n]);
                h[n] = fmaf(mv.y, w.y, h[n]);
                h[n] = fmaf(mv.z, w.z, h[n]);
                h[n] = fmaf(mv.w, w.w, h[n]);
            }
        }
#pragma unroll
        for (int n = 0; n < 9; ++n) h1s[tl][n * 64 + lane] = fmaxf(h[n], 0.0f);
    }
    __syncthreads();

    // wB phase: thread (half, l) does 2 targets
#pragma unroll
    for (int tt = 0; tt < 2; ++tt) {
        const int tgt = half * 2 + tt;
        float acc = -INFINITY;
        for (int n = 0; n < 9; ++n) {
            float s = bBl;
            for (int k = 0; k < 64; k += 4) {
                const float4 hv = *(const float4*)&h1s[tgt][n * 64 + k];
                s = fmaf(hv.x, wcol[k + 0], s);
                s = fmaf(hv.y, wcol[k + 1], s);
                s = fmaf(hv.z, wcol[k + 2], s);
                s = fmaf(hv.w, wcol[k + 3], s);
            }
            acc = fmaxf(acc, s);
        }
        row[tgt][l] = fmaxf(acc, 0.0f);
    }
    __syncthreads();

    // head + log_softmax
    if (tid < 20) {
        const int tgt = tid / 5, o = tid % 5;
        float s = bcs[o];
        for (int k = 0; k < 128; ++k) s += row[tgt][k] * wc[k * 5 + o];
        sv[tgt][o] = s;
    }
    __syncthreads();
    if (tid < 20) {
        const int tgt = tid / 5, o = tid % 5;
        float m = sv[tgt][0];
#pragma unroll
        for (int q = 1; q < 5; ++q) m = fmaxf(m, sv[tgt][q]);
        float sum = 0.0f;
#pragma unroll
        for (int q = 0; q < 5; ++q) sum += expf(sv[tgt][q] - m);
        const float lse = m + logf(sum);
        stf(out, (blockIdx.x * 4 + tgt) * 5 + o, sv[tgt][o] - lse);
    }
}

// ---------------------------------------------------------------------------
extern "C" void kernel_launch(void* const* d_in, const int* in_sizes, int n_in,
                              void* d_out, int out_size, void* d_ws, size_t ws_size,
                              hipStream_t stream) {
    if (ws_size < (size_t)WS_NEEDED) return;

    char* ws = (char*)d_ws;
    int*   flag = (int*)(ws + WS_FLAG_OFF);
    int*   idx  = (int*)(ws + WS_IDX_OFF);
    float* x1   = (float*)(ws + WS_X1_OFF);

    sniff_kernel<<<1, 256, 0, stream>>>((const unsigned short*)d_in[0], flag);

    {
        typedef __hip_bfloat16 T;
        const T* pos = (const T*)d_in[0];
        knn_kernel<T><<<N_PTS / 4, 256, 0, stream>>>(pos, flag, DT_BF16, idx);
        conv1_kernel<T><<<N_PTS / 4, 256, 0, stream>>>(pos, flag, DT_BF16, idx,
            (const T*)d_in[1], (const T*)d_in[2], (const T*)d_in[3], (const T*)d_in[4], x1);
        conv2_head_kernel<T><<<N_PTS / 4, 256, 0, stream>>>(pos, flag, DT_BF16, idx, x1,
            (const T*)d_in[5], (const T*)d_in[6], (const T*)d_in[7], (const T*)d_in[8],
            (const T*)d_in[9], (const T*)d_in[10], (T*)d_out);
    }
    {
        typedef float T;
        const T* pos = (const T*)d_in[0];
        knn_kernel<T><<<N_PTS / 4, 256, 0, stream>>>(pos, flag, DT_FP32, idx);
        conv1_kernel<T><<<N_PTS / 4, 256, 0, stream>>>(pos, flag, DT_FP32, idx,
            (const T*)d_in[1], (const T*)d_in[2], (const T*)d_in[3], (const T*)d_in[4], x1);
        conv2_head_kernel<T><<<N_PTS / 4, 256, 0, stream>>>(pos, flag, DT_FP32, idx, x1,
            (const T*)d_in[5], (const T*)d_in[6], (const T*)d_in[7], (const T*)d_in[8],
            (const T*)d_in[9], (const T*)d_in[10], (T*)d_out);
    }
}

// Round 2
// 386.576 us; speedup vs baseline: 1.4854x; 1.4507x over previous
//
#include <hip/hip_runtime.h>
#include <hip/hip_bf16.h>
#include <math.h>

#define N_PTS 16384
#define KNN 8

#define DT_BF16 1
#define DT_FP32 2

// Workspace layout:
//   flag : int          @ 0
//   idx  : int  [N*9]   @ 64        -> 589,824 B
//   x1   : f32  [N*64]  @ 589,888   -> 4,194,304 B
// Grid-KNN scratch lives INSIDE the x1 region (consumed before conv1 writes x1):
//   cnt    : int [32768]   @ x1+0
//   start  : int [32768]   @ x1+131072
//   cursor : int [32768]   @ x1+262144
//   pid    : int [16384]   @ x1+393216
//   pts4   : f4  [16384]   @ x1+458752   (total 720,896 <= 4,194,304)
#define WS_FLAG_OFF 0
#define WS_IDX_OFF  64
#define WS_X1_OFF   589888
#define WS_NEEDED   4784192

#define WS_CNT_OFF    (WS_X1_OFF)
#define WS_START_OFF  (WS_X1_OFF + 131072)
#define WS_CURSOR_OFF (WS_X1_OFF + 262144)
#define WS_PID_OFF    (WS_X1_OFF + 393216)
#define WS_PTS_OFF    (WS_X1_OFF + 458752)

#define GRID_R  32
#define NCELLS  (GRID_R * GRID_R * GRID_R)
#define GLO     -4.5f
#define CELL_E  0.28125f
#define CELL_INV 3.5555556f

__device__ __forceinline__ float bf2f(__hip_bfloat16 v) { return __bfloat162float(v); }

__device__ __forceinline__ float ldf(const float* p, int i) { return p[i]; }
__device__ __forceinline__ float ldf(const __hip_bfloat16* p, int i) { return bf2f(p[i]); }
__device__ __forceinline__ void stf(float* p, int i, float v) { p[i] = v; }
__device__ __forceinline__ void stf(__hip_bfloat16* p, int i, float v) { p[i] = __float2bfloat16(v); }

__device__ __forceinline__ int clamp_idx(int j) {
    return ((unsigned)j < (unsigned)N_PTS) ? j : 0;
}

__device__ __forceinline__ int cell_of(float v) {
    int c = (int)((v - GLO) * CELL_INV);   // trunc==floor for >=0; negatives clamp to 0 anyway
    return min(max(c, 0), GRID_R - 1);
}

// ---------------------------------------------------------------------------
// Kernel 0: dtype sniffer (unchanged).
// ---------------------------------------------------------------------------
__global__ __launch_bounds__(256) void sniff_kernel(const unsigned short* __restrict__ posu,
                                                    int* __restrict__ flag) {
    __shared__ int red[256];
    int local = 0;
    for (int e = threadIdx.x; e < 3 * N_PTS; e += 256) {
        const float v = __uint_as_float(((unsigned)posu[e]) << 16);
        if (!(fabsf(v) <= 64.0f)) local++;
    }
    red[threadIdx.x] = local;
    __syncthreads();
    for (int s = 128; s > 0; s >>= 1) {
        if (threadIdx.x < s) red[threadIdx.x] += red[threadIdx.x + s];
        __syncthreads();
    }
    if (threadIdx.x == 0) flag[0] = (red[0] > 16) ? DT_FP32 : DT_BF16;
}

// ---------------------------------------------------------------------------
// Grid build: zero -> count -> scan -> scatter.
// ---------------------------------------------------------------------------
__global__ __launch_bounds__(256) void grid_zero_kernel(int* __restrict__ cnt) {
    cnt[blockIdx.x * 256 + threadIdx.x] = 0;
}

template <typename T>
__global__ __launch_bounds__(256) void grid_count_kernel(const T* __restrict__ pos,
                                                         const int* __restrict__ flag, int want,
                                                         int* __restrict__ cnt) {
    if (flag[0] != want) return;
    const int i = blockIdx.x * 256 + threadIdx.x;
    const float x = ldf(pos, 3 * i + 0);
    const float y = ldf(pos, 3 * i + 1);
    const float z = ldf(pos, 3 * i + 2);
    const int c = (cell_of(z) * GRID_R + cell_of(y)) * GRID_R + cell_of(x);
    atomicAdd(&cnt[c], 1);
}

__global__ __launch_bounds__(1024) void grid_scan_kernel(const int* __restrict__ cnt,
                                                         int* __restrict__ start,
                                                         int* __restrict__ cursor) {
    __shared__ int part[1024];
    const int t = threadIdx.x;
    const int base = t * 32;
    int s = 0;
    for (int k = 0; k < 32; ++k) s += cnt[base + k];
    part[t] = s;
    __syncthreads();
    for (int off = 1; off < 1024; off <<= 1) {
        int v = (t >= off) ? part[t - off] : 0;
        __syncthreads();
        part[t] += v;
        __syncthreads();
    }
    int run = (t == 0) ? 0 : part[t - 1];
    for (int k = 0; k < 32; ++k) {
        start[base + k] = run;
        cursor[base + k] = run;
        run += cnt[base + k];
    }
}

template <typename T>
__global__ __launch_bounds__(256) void grid_scatter_kernel(const T* __restrict__ pos,
                                                           const int* __restrict__ flag, int want,
                                                           int* __restrict__ cursor,
                                                           float4* __restrict__ pts4,
                                                           int* __restrict__ pid) {
    if (flag[0] != want) return;
    const int i = blockIdx.x * 256 + threadIdx.x;
    const float x = ldf(pos, 3 * i + 0);
    const float y = ldf(pos, 3 * i + 1);
    const float z = ldf(pos, 3 * i + 2);
    const int c = (cell_of(z) * GRID_R + cell_of(y)) * GRID_R + cell_of(x);
    const int slot = atomicAdd(&cursor[c], 1);
    const float sq = fmaf(x, x, fmaf(y, y, z * z));
    pts4[slot] = make_float4(-2.0f * x, -2.0f * y, -2.0f * z, sq);
    pid[slot] = i;
}

// ---------------------------------------------------------------------------
// Kernel 1: grid KNN. One 64-lane wave per target; ring expansion over cells.
// Per-candidate arithmetic identical to the passing O(N^2) kernel (d' =
// sq_j - 2 dot, same fma order). Full lex (d, idx) ordering everywhere =>
// output invariant to atomic scatter order and matches stable top_k ties.
// Termination after ring r: strict  d8_real < m^2  where m = min distance
// from target to the unscanned region (faces at the grid edge => INF, since
// out-of-range points are clamped into scanned boundary cells).
// ---------------------------------------------------------------------------
template <typename T>
__global__ __launch_bounds__(256) void knn_grid_kernel(const T* __restrict__ pos,
                                                       const int* __restrict__ flag, int want,
                                                       const int* __restrict__ cstart,
                                                       const int* __restrict__ ccnt,
                                                       const float4* __restrict__ pts4,
                                                       const int* __restrict__ pid,
                                                       int* __restrict__ idx_out) {
    if (flag[0] != want) return;

    const int tid  = threadIdx.x;
    const int wv   = tid >> 6;
    const int lane = tid & 63;
    const int i    = blockIdx.x * 4 + wv;

    const float pix = ldf(pos, 3 * i + 0);
    const float piy = ldf(pos, 3 * i + 1);
    const float piz = ldf(pos, 3 * i + 2);
    const float sqi = fmaf(pix, pix, fmaf(piy, piy, piz * piz));
    const int cx = cell_of(pix), cy = cell_of(piy), cz = cell_of(piz);

    float bd[KNN];
    int   bi[KNN];
#pragma unroll
    for (int q = 0; q < KNN; ++q) { bd[q] = INFINITY; bi[q] = 0x7fffffff; }
    float tau = INFINITY;   // filter bound in d' space (>= global 8th-best)

    for (int r = 1; r <= GRID_R; ++r) {
        const int W = 2 * r + 1, W2 = W * W, vol = W2 * W;
        for (int t0 = lane; t0 < vol; t0 += 64) {
            int dz = t0 / W2;
            int rem = t0 - dz * W2;
            int dy = rem / W;
            int dx = rem - dy * W;
            dx -= r; dy -= r; dz -= r;
            if (r > 1) {   // ring only (r==1 scans the full 3x3x3 incl. own cell)
                const int ax = dx < 0 ? -dx : dx;
                const int ay = dy < 0 ? -dy : dy;
                const int az = dz < 0 ? -dz : dz;
                if (max(ax, max(ay, az)) != r) continue;
            }
            const int ccx = cx + dx, ccy = cy + dy, ccz = cz + dz;
            if ((unsigned)ccx >= GRID_R || (unsigned)ccy >= GRID_R || (unsigned)ccz >= GRID_R)
                continue;
            const int c  = (ccz * GRID_R + ccy) * GRID_R + ccx;
            const int s0 = cstart[c];
            const int n  = ccnt[c];
            for (int s = s0; s < s0 + n; ++s) {
                const float4 cq = pts4[s];
                const int    pj = pid[s];
                const float d = fmaf(cq.x, pix, fmaf(cq.y, piy, fmaf(cq.z, piz, cq.w)));
                if (pj == i) continue;            // exclude self
                if (d <= tau) {                   // <= : lex-safe at the boundary
                    float cd = d; int ci = pj;
#pragma unroll
                    for (int q = 0; q < KNN; ++q) {
                        const bool ins = (cd < bd[q]) || (cd == bd[q] && ci < bi[q]);
                        const float nd = ins ? cd : bd[q];
                        const int   ni = ins ? ci : bi[q];
                        const float od = ins ? bd[q] : cd;
                        const int   oi = ins ? bi[q] : ci;
                        bd[q] = nd; bi[q] = ni; cd = od; ci = oi;
                    }
                    tau = fminf(tau, bd[KNN - 1]);
                }
            }
        }

        // ---- termination check ----
        float wtau = bd[KNN - 1];
#pragma unroll
        for (int s = 1; s < 64; s <<= 1) wtau = fminf(wtau, __shfl_xor(wtau, s, 64));
        int cl = 0;
#pragma unroll
        for (int q = 0; q < KNN; ++q) cl += (bd[q] < INFINITY) ? 1 : 0;
#pragma unroll
        for (int s = 1; s < 64; s <<= 1) cl += __shfl_xor(cl, s, 64);

        float mg = INFINITY;
        bool full = true;
        if (cx - r > 0)          { mg = fminf(mg, pix - (GLO + (float)(cx - r) * CELL_E));     full = false; }
        if (cx + r < GRID_R - 1) { mg = fminf(mg, (GLO + (float)(cx + r + 1) * CELL_E) - pix); full = false; }
        if (cy - r > 0)          { mg = fminf(mg, piy - (GLO + (float)(cy - r) * CELL_E));     full = false; }
        if (cy + r < GRID_R - 1) { mg = fminf(mg, (GLO + (float)(cy + r + 1) * CELL_E) - piy); full = false; }
        if (cz - r > 0)          { mg = fminf(mg, piz - (GLO + (float)(cz - r) * CELL_E));     full = false; }
        if (cz + r < GRID_R - 1) { mg = fminf(mg, (GLO + (float)(cz + r + 1) * CELL_E) - piz); full = false; }

        if (full) break;                          // whole grid scanned -> exact
        if (cl >= 8) {
            const float need = mg * mg - sqi;     // d' < need  <=>  d_real < m^2
            if (wtau < need) break;               // conservative fast path
            // exact global 8th-best via destructive merge of list copies
            float cd2[KNN]; int ci2[KNN];
#pragma unroll
            for (int q = 0; q < KNN; ++q) { cd2[q] = bd[q]; ci2[q] = bi[q]; }
            float d8 = INFINITY;
#pragma unroll
            for (int k = 0; k < KNN; ++k) {
                float dw = cd2[0];
                int   iw = ci2[0];
#pragma unroll
                for (int s = 1; s < 64; s <<= 1) {
                    const float od = __shfl_xor(dw, s, 64);
                    const int   oi = __shfl_xor(iw, s, 64);
                    if (od < dw || (od == dw && oi < iw)) { dw = od; iw = oi; }
                }
                if (cd2[0] == dw && ci2[0] == iw) {
#pragma unroll
                    for (int q = 0; q < KNN - 1; ++q) { cd2[q] = cd2[q + 1]; ci2[q] = ci2[q + 1]; }
                    cd2[KNN - 1] = INFINITY; ci2[KNN - 1] = 0x7fffffff;
                }
                d8 = dw;
            }
            if (d8 < need) break;                 // strict: ties at boundary keep scanning
            tau = fminf(tau, d8);                 // exact bound tightens the filter
        }
        tau = fminf(tau, wtau);                   // share across lanes for next ring
    }

    // ---- final merge of 64 sorted lists (lex), emit top-8 ----
#pragma unroll
    for (int k = 0; k < KNN; ++k) {
        float dw = bd[0];
        int   iw = bi[0];
#pragma unroll
        for (int s = 1; s < 64; s <<= 1) {
            const float od = __shfl_xor(dw, s, 64);
            const int   oi = __shfl_xor(iw, s, 64);
            if (od < dw || (od == dw && oi < iw)) { dw = od; iw = oi; }
        }
        if (bd[0] == dw && bi[0] == iw) {
#pragma unroll
            for (int q = 0; q < KNN - 1; ++q) { bd[q] = bd[q + 1]; bi[q] = bi[q + 1]; }
            bd[KNN - 1] = INFINITY; bi[KNN - 1] = 0x7fffffff;
        }
        if (lane == 0) idx_out[i * 9 + k] = clamp_idx(iw);
    }
    if (lane == 0) idx_out[i * 9 + 8] = i;
}

// ---------------------------------------------------------------------------
// Kernel 2: conv1 (unchanged).
// ---------------------------------------------------------------------------
template <typename T>
__global__ __launch_bounds__(256) void conv1_kernel(const T* __restrict__ pos,
                                                    const int* __restrict__ flag, int want,
                                                    const int* __restrict__ idx,
                                                    const T* __restrict__ W1a,
                                                    const T* __restrict__ b1a,
                                                    const T* __restrict__ W1b,
                                                    const T* __restrict__ b1b,
                                                    float* __restrict__ x1) {
    if (flag[0] != want) return;

    __shared__ float wA[6 * 32];
    __shared__ float bA[32];
    __shared__ float wB[32 * 64];
    __shared__ float bB[64];
    __shared__ float msg[4][9][6];
    __shared__ float h1s[4][9 * 32];

    const int tid = threadIdx.x;
    for (int e = tid; e < 192; e += 256) wA[e] = ldf(W1a, e);
    if (tid < 32) bA[tid] = ldf(b1a, tid);
    for (int e = tid; e < 2048; e += 256) wB[e] = ldf(W1b, e);
    if (tid < 64) bB[tid] = ldf(b1b, tid);

    const int tl   = tid >> 6;
    const int lane = tid & 63;
    const int i    = blockIdx.x * 4 + tl;

    if (lane < 54) {
        const int n = lane / 6, c = lane % 6;
        const int j = clamp_idx(idx[i * 9 + n]);
        float v = ldf(pos, 3 * j + (c % 3));
        if (c >= 3) v -= ldf(pos, 3 * i + (c - 3));
        msg[tl][n][c] = v;
    }
    __syncthreads();

    for (int e = lane; e < 288; e += 64) {
        const int n = e >> 5, k = e & 31;
        float s = bA[k];
#pragma unroll
        for (int c = 0; c < 6; ++c) s += msg[tl][n][c] * wA[c * 32 + k];
        h1s[tl][n * 32 + k] = fmaxf(s, 0.0f);
    }
    __syncthreads();

    float wcol[32];
#pragma unroll
    for (int k = 0; k < 32; ++k) wcol[k] = wB[k * 64 + lane];

    float acc = -INFINITY;
    for (int n = 0; n < 9; ++n) {
        float s = bB[lane];
#pragma unroll
        for (int k = 0; k < 32; ++k) s += h1s[tl][n * 32 + k] * wcol[k];
        acc = fmaxf(acc, s);
    }
    x1[i * 64 + lane] = fmaxf(acc, 0.0f);
}

// ---------------------------------------------------------------------------
// Kernel 3: conv2 + head (unchanged).
// ---------------------------------------------------------------------------
template <typename T>
__global__ __launch_bounds__(256) void conv2_head_kernel(const T* __restrict__ pos,
                                                         const int* __restrict__ flag, int want,
                                                         const int* __restrict__ idx,
                                                         const float* __restrict__ x1,
                                                         const T* __restrict__ W2a,
                                                         const T* __restrict__ b2a,
                                                         const T* __restrict__ W2b,
                                                         const T* __restrict__ b2b,
                                                         const T* __restrict__ Wc,
                                                         const T* __restrict__ bc,
                                                         T* __restrict__ out) {
    if (flag[0] != want) return;

    __shared__ float wAT[64 * 68];
    __shared__ float bA[64];
    __shared__ float wc[640];
    __shared__ float bcs[5];
    __shared__ float msg[4][9 * 68];
    __shared__ float h1s[4][9 * 64];
    __shared__ float row[4][128];
    __shared__ float sv[4][5];

    const int tid  = threadIdx.x;
    const int l    = tid & 127;
    const int half = tid >> 7;

    float wcol[64];
#pragma unroll
    for (int k = 0; k < 64; ++k) wcol[k] = ldf(W2b, k * 128 + l);
    const float bBl = ldf(b2b, l);

    for (int e = tid; e < 4288; e += 256) {
        const int c = e >> 6, k = e & 63;
        wAT[k * 68 + c] = ldf(W2a, e);
    }
    if (tid < 64) wAT[tid * 68 + 67] = 0.0f;
    if (tid < 64) bA[tid] = ldf(b2a, tid);
    for (int e = tid; e < 640; e += 256) wc[e] = ldf(Wc, e);
    if (tid < 5) bcs[tid] = ldf(bc, tid);

    const int tl   = tid >> 6;
    const int lane = tid & 63;
    const int i    = blockIdx.x * 4 + tl;

    for (int e = lane; e < 603; e += 64) {
        const int n = e / 67, c = e % 67;
        const int j = clamp_idx(idx[i * 9 + n]);
        float v;
        if (c < 64) v = x1[j * 64 + c];
        else        v = ldf(pos, 3 * j + (c - 64)) - ldf(pos, 3 * i + (c - 64));
        msg[tl][n * 68 + c] = v;
    }
    if (lane < 9) msg[tl][lane * 68 + 67] = 0.0f;
    __syncthreads();

    {
        float h[9];
#pragma unroll
        for (int n = 0; n < 9; ++n) h[n] = bA[lane];
        for (int c = 0; c < 68; c += 4) {
            const float4 w = *(const float4*)&wAT[lane * 68 + c];
#pragma unroll
            for (int n = 0; n < 9; ++n) {
                const float4 mv = *(const float4*)&msg[tl][n * 68 + c];
                h[n] = fmaf(mv.x, w.x, h[n]);
                h[n] = fmaf(mv.y, w.y, h[n]);
                h[n] = fmaf(mv.z, w.z, h[n]);
                h[n] = fmaf(mv.w, w.w, h[n]);
            }
        }
#pragma unroll
        for (int n = 0; n < 9; ++n) h1s[tl][n * 64 + lane] = fmaxf(h[n], 0.0f);
    }
    __syncthreads();

#pragma unroll
    for (int tt = 0; tt < 2; ++tt) {
        const int tgt = half * 2 + tt;
        float acc = -INFINITY;
        for (int n = 0; n < 9; ++n) {
            float s = bBl;
            for (int k = 0; k < 64; k += 4) {
                const float4 hv = *(const float4*)&h1s[tgt][n * 64 + k];
                s = fmaf(hv.x, wcol[k + 0], s);
                s = fmaf(hv.y, wcol[k + 1], s);
                s = fmaf(hv.z, wcol[k + 2], s);
                s = fmaf(hv.w, wcol[k + 3], s);
            }
            acc = fmaxf(acc, s);
        }
        row[tgt][l] = fmaxf(acc, 0.0f);
    }
    __syncthreads();

    if (tid < 20) {
        const int tgt = tid / 5, o = tid % 5;
        float s = bcs[o];
        for (int k = 0; k < 128; ++k) s += row[tgt][k] * wc[k * 5 + o];
        sv[tgt][o] = s;
    }
    __syncthreads();
    if (tid < 20) {
        const int tgt = tid / 5, o = tid % 5;
        float m = sv[tgt][0];
#pragma unroll
        for (int q = 1; q < 5; ++q) m = fmaxf(m, sv[tgt][q]);
        float sum = 0.0f;
#pragma unroll
        for (int q = 0; q < 5; ++q) sum += expf(sv[tgt][q] - m);
        const float lse = m + logf(sum);
        stf(out, (blockIdx.x * 4 + tgt) * 5 + o, sv[tgt][o] - lse);
    }
}

// ---------------------------------------------------------------------------
extern "C" void kernel_launch(void* const* d_in, const int* in_sizes, int n_in,
                              void* d_out, int out_size, void* d_ws, size_t ws_size,
                              hipStream_t stream) {
    if (ws_size < (size_t)WS_NEEDED) return;

    char* ws = (char*)d_ws;
    int*    flag   = (int*)(ws + WS_FLAG_OFF);
    int*    idx    = (int*)(ws + WS_IDX_OFF);
    float*  x1     = (float*)(ws + WS_X1_OFF);
    int*    cnt    = (int*)(ws + WS_CNT_OFF);
    int*    cstart = (int*)(ws + WS_START_OFF);
    int*    cursor = (int*)(ws + WS_CURSOR_OFF);
    int*    pid    = (int*)(ws + WS_PID_OFF);
    float4* pts4   = (float4*)(ws + WS_PTS_OFF);

    sniff_kernel<<<1, 256, 0, stream>>>((const unsigned short*)d_in[0], flag);

    // grid build (scan is dtype-independent; count/scatter are flag-guarded)
    grid_zero_kernel<<<NCELLS / 256, 256, 0, stream>>>(cnt);
    grid_count_kernel<__hip_bfloat16><<<N_PTS / 256, 256, 0, stream>>>(
        (const __hip_bfloat16*)d_in[0], flag, DT_BF16, cnt);
    grid_count_kernel<float><<<N_PTS / 256, 256, 0, stream>>>(
        (const float*)d_in[0], flag, DT_FP32, cnt);
    grid_scan_kernel<<<1, 1024, 0, stream>>>(cnt, cstart, cursor);
    grid_scatter_kernel<__hip_bfloat16><<<N_PTS / 256, 256, 0, stream>>>(
        (const __hip_bfloat16*)d_in[0], flag, DT_BF16, cursor, pts4, pid);
    grid_scatter_kernel<float><<<N_PTS / 256, 256, 0, stream>>>(
        (const float*)d_in[0], flag, DT_FP32, cursor, pts4, pid);

    {
        typedef __hip_bfloat16 T;
        const T* pos = (const T*)d_in[0];
        knn_grid_kernel<T><<<N_PTS / 4, 256, 0, stream>>>(pos, flag, DT_BF16,
            cstart, cnt, pts4, pid, idx);
        conv1_kernel<T><<<N_PTS / 4, 256, 0, stream>>>(pos, flag, DT_BF16, idx,
            (const T*)d_in[1], (const T*)d_in[2], (const T*)d_in[3], (const T*)d_in[4], x1);
        conv2_head_kernel<T><<<N_PTS / 4, 256, 0, stream>>>(pos, flag, DT_BF16, idx, x1,
            (const T*)d_in[5], (const T*)d_in[6], (const T*)d_in[7], (const T*)d_in[8],
            (const T*)d_in[9], (const T*)d_in[10], (T*)d_out);
    }
    {
        typedef float T;
        const T* pos = (const T*)d_in[0];
        knn_grid_kernel<T><<<N_PTS / 4, 256, 0, stream>>>(pos, flag, DT_FP32,
            cstart, cnt, pts4, pid, idx);
        conv1_kernel<T><<<N_PTS / 4, 256, 0, stream>>>(pos, flag, DT_FP32, idx,
            (const T*)d_in[1], (const T*)d_in[2], (const T*)d_in[3], (const T*)d_in[4], x1);
        conv2_head_kernel<T><<<N_PTS / 4, 256, 0, stream>>>(pos, flag, DT_FP32, idx, x1,
            (const T*)d_in[5], (const T*)d_in[6], (const T*)d_in[7], (const T*)d_in[8],
            (const T*)d_in[9], (const T*)d_in[10], (T*)d_out);
    }
}

// Round 3
// 361.682 us; speedup vs baseline: 1.5877x; 1.0688x over previous
//
#include <hip/hip_runtime.h>
#include <hip/hip_bf16.h>
#include <math.h>

#define N_PTS 16384
#define KNN 8

#define DT_BF16 1
#define DT_FP32 2

// Workspace layout:
//   flag : int          @ 0
//   idx  : int  [N*9]   @ 64        -> 589,824 B
//   x1   : f32  [N*64]  @ 589,888   -> 4,194,304 B
// Grid-KNN scratch lives INSIDE the x1 region (dead before conv1 writes x1):
//   cnt    : int [32768]   @ x1+0
//   start  : int [32768]   @ x1+131072
//   cursor : int [32768]   @ x1+262144
//   pid    : int [16384]   @ x1+393216
//   pts4   : f4  [16384]   @ x1+458752
#define WS_FLAG_OFF 0
#define WS_IDX_OFF  64
#define WS_X1_OFF   589888
#define WS_NEEDED   4784192

#define WS_CNT_OFF    (WS_X1_OFF)
#define WS_START_OFF  (WS_X1_OFF + 131072)
#define WS_CURSOR_OFF (WS_X1_OFF + 262144)
#define WS_PID_OFF    (WS_X1_OFF + 393216)
#define WS_PTS_OFF    (WS_X1_OFF + 458752)

#define GRID_R  32
#define NCELLS  (GRID_R * GRID_R * GRID_R)
#define GLO     -4.5f
#define CELL_E  0.28125f
#define CELL_INV 3.5555556f

__device__ __forceinline__ float bf2f(__hip_bfloat16 v) { return __bfloat162float(v); }

__device__ __forceinline__ float ldf(const float* p, int i) { return p[i]; }
__device__ __forceinline__ float ldf(const __hip_bfloat16* p, int i) { return bf2f(p[i]); }
__device__ __forceinline__ void stf(float* p, int i, float v) { p[i] = v; }
__device__ __forceinline__ void stf(__hip_bfloat16* p, int i, float v) { p[i] = __float2bfloat16(v); }

__device__ __forceinline__ int clamp_idx(int j) {
    return ((unsigned)j < (unsigned)N_PTS) ? j : 0;
}

__device__ __forceinline__ int cell_of(float v) {
    int c = (int)((v - GLO) * CELL_INV);
    return min(max(c, 0), GRID_R - 1);
}

// flag[0] holds the sniffer's bad-count; >16 => fp32 input.
__device__ __forceinline__ int get_dt(const int* flag) {
    return (flag[0] > 16) ? DT_FP32 : DT_BF16;
}

// ---------------------------------------------------------------------------
// zero: cnt[] and flag.
// ---------------------------------------------------------------------------
__global__ __launch_bounds__(256) void zero_kernel(int* __restrict__ cnt, int* __restrict__ flag) {
    const int e = blockIdx.x * 256 + threadIdx.x;
    cnt[e] = 0;
    if (e == 0) flag[0] = 0;
}

// ---------------------------------------------------------------------------
// sniff: multi-block (was 1 block = serial tail). Each block reduces locally,
// one atomicAdd into flag.
// ---------------------------------------------------------------------------
__global__ __launch_bounds__(256) void sniff_kernel(const unsigned short* __restrict__ posu,
                                                    int* __restrict__ flag) {
    __shared__ int red[256];
    int local = 0;
    for (int e = blockIdx.x * 256 + threadIdx.x; e < 3 * N_PTS; e += 64 * 256) {
        const float v = __uint_as_float(((unsigned)posu[e]) << 16);
        if (!(fabsf(v) <= 64.0f)) local++;
    }
    red[threadIdx.x] = local;
    __syncthreads();
    for (int s = 128; s > 0; s >>= 1) {
        if (threadIdx.x < s) red[threadIdx.x] += red[threadIdx.x + s];
        __syncthreads();
    }
    if (threadIdx.x == 0 && red[0] > 0) atomicAdd(flag, red[0]);
}

// ---------------------------------------------------------------------------
// Grid build: count -> scan -> scatter (dtype fused inside each kernel).
// ---------------------------------------------------------------------------
template <typename T>
__device__ __forceinline__ void count_body(const T* __restrict__ pos, int* __restrict__ cnt) {
    const int i = blockIdx.x * 256 + threadIdx.x;
    const float x = ldf(pos, 3 * i + 0);
    const float y = ldf(pos, 3 * i + 1);
    const float z = ldf(pos, 3 * i + 2);
    const int c = (cell_of(z) * GRID_R + cell_of(y)) * GRID_R + cell_of(x);
    atomicAdd(&cnt[c], 1);
}

__global__ __launch_bounds__(256) void grid_count_kernel(const void* __restrict__ pos,
                                                         const int* __restrict__ flag,
                                                         int* __restrict__ cnt) {
    if (get_dt(flag) == DT_BF16) count_body<__hip_bfloat16>((const __hip_bfloat16*)pos, cnt);
    else                         count_body<float>((const float*)pos, cnt);
}

__global__ __launch_bounds__(1024) void grid_scan_kernel(const int* __restrict__ cnt,
                                                         int* __restrict__ start,
                                                         int* __restrict__ cursor) {
    __shared__ int part[1024];
    const int t = threadIdx.x;
    const int base = t * 32;
    int s = 0;
    for (int k = 0; k < 32; ++k) s += cnt[base + k];
    part[t] = s;
    __syncthreads();
    for (int off = 1; off < 1024; off <<= 1) {
        int v = (t >= off) ? part[t - off] : 0;
        __syncthreads();
        part[t] += v;
        __syncthreads();
    }
    int run = (t == 0) ? 0 : part[t - 1];
    for (int k = 0; k < 32; ++k) {
        start[base + k] = run;
        cursor[base + k] = run;
        run += cnt[base + k];
    }
}

template <typename T>
__device__ __forceinline__ void scatter_body(const T* __restrict__ pos, int* __restrict__ cursor,
                                             float4* __restrict__ pts4, int* __restrict__ pid) {
    const int i = blockIdx.x * 256 + threadIdx.x;
    const float x = ldf(pos, 3 * i + 0);
    const float y = ldf(pos, 3 * i + 1);
    const float z = ldf(pos, 3 * i + 2);
    const int c = (cell_of(z) * GRID_R + cell_of(y)) * GRID_R + cell_of(x);
    const int slot = atomicAdd(&cursor[c], 1);
    const float sq = fmaf(x, x, fmaf(y, y, z * z));
    pts4[slot] = make_float4(-2.0f * x, -2.0f * y, -2.0f * z, sq);
    pid[slot] = i;
}

__global__ __launch_bounds__(256) void grid_scatter_kernel(const void* __restrict__ pos,
                                                           const int* __restrict__ flag,
                                                           int* __restrict__ cursor,
                                                           float4* __restrict__ pts4,
                                                           int* __restrict__ pid) {
    if (get_dt(flag) == DT_BF16) scatter_body<__hip_bfloat16>((const __hip_bfloat16*)pos, cursor, pts4, pid);
    else                         scatter_body<float>((const float*)pos, cursor, pts4, pid);
}

// ---------------------------------------------------------------------------
// KNN v4: one wave per target. Phase A = compile-time 5x5x5 window (125 slots,
// constant divisors -> magic-mul, 2 wave-iters; ~97% of targets terminate
// here since min margin = 2*CELL_E = 0.56 >> typical d8 ~ 0.15). Generic
// ring loop (runtime divisions) only for the rare tail. Lex (d, idx) order
// everywhere -> invariant to scatter order, matches stable top_k ties.
// ---------------------------------------------------------------------------
template <typename T>
__device__ void knn_body(const T* __restrict__ pos,
                         const int* __restrict__ cstart, const int* __restrict__ ccnt,
                         const float4* __restrict__ pts4, const int* __restrict__ pid,
                         int* __restrict__ idx_out) {
    const int tid  = threadIdx.x;
    const int wv   = tid >> 6;
    const int lane = tid & 63;
    const int i    = blockIdx.x * 4 + wv;

    const float pix = ldf(pos, 3 * i + 0);
    const float piy = ldf(pos, 3 * i + 1);
    const float piz = ldf(pos, 3 * i + 2);
    const float sqi = fmaf(pix, pix, fmaf(piy, piy, piz * piz));
    const int cx = cell_of(pix), cy = cell_of(piy), cz = cell_of(piz);

    float bd[KNN];
    int   bi[KNN];
#pragma unroll
    for (int q = 0; q < KNN; ++q) { bd[q] = INFINITY; bi[q] = 0x7fffffff; }
    float tau = INFINITY;

    auto scan_cell = [&](int ccx, int ccy, int ccz) {
        const int c  = (ccz * GRID_R + ccy) * GRID_R + ccx;
        const int s0 = cstart[c];
        const int n  = ccnt[c];
        for (int s = s0; s < s0 + n; ++s) {
            const float4 cq = pts4[s];
            const int    pj = pid[s];
            const float d = fmaf(cq.x, pix, fmaf(cq.y, piy, fmaf(cq.z, piz, cq.w)));
            if (pj == i) continue;
            if (d <= tau) {
                float cd = d; int ci = pj;
#pragma unroll
                for (int q = 0; q < KNN; ++q) {
                    const bool ins = (cd < bd[q]) || (cd == bd[q] && ci < bi[q]);
                    const float nd = ins ? cd : bd[q];
                    const int   ni = ins ? ci : bi[q];
                    const float od = ins ? bd[q] : cd;
                    const int   oi = ins ? bi[q] : ci;
                    bd[q] = nd; bi[q] = ni; cd = od; ci = oi;
                }
                tau = fminf(tau, bd[KNN - 1]);
            }
        }
    };

    // Termination after scanning all cells with Chebyshev radius <= r.
    // Returns true when provably exact; tightens tau as a side effect.
    auto term_check = [&](int r) -> bool {
        float wtau = bd[KNN - 1];
#pragma unroll
        for (int s = 1; s < 64; s <<= 1) wtau = fminf(wtau, __shfl_xor(wtau, s, 64));
        int cl = 0;
#pragma unroll
        for (int q = 0; q < KNN; ++q) cl += (bd[q] < INFINITY) ? 1 : 0;
#pragma unroll
        for (int s = 1; s < 64; s <<= 1) cl += __shfl_xor(cl, s, 64);

        float mg = INFINITY;
        bool full = true;
        if (cx - r > 0)          { mg = fminf(mg, pix - (GLO + (float)(cx - r) * CELL_E));     full = false; }
        if (cx + r < GRID_R - 1) { mg = fminf(mg, (GLO + (float)(cx + r + 1) * CELL_E) - pix); full = false; }
        if (cy - r > 0)          { mg = fminf(mg, piy - (GLO + (float)(cy - r) * CELL_E));     full = false; }
        if (cy + r < GRID_R - 1) { mg = fminf(mg, (GLO + (float)(cy + r + 1) * CELL_E) - piy); full = false; }
        if (cz - r > 0)          { mg = fminf(mg, piz - (GLO + (float)(cz - r) * CELL_E));     full = false; }
        if (cz + r < GRID_R - 1) { mg = fminf(mg, (GLO + (float)(cz + r + 1) * CELL_E) - piz); full = false; }

        if (full) return true;
        if (cl >= 8) {
            const float need = mg * mg - sqi;      // d_real < m^2  <=>  d' < need
            if (wtau < need) { tau = fminf(tau, wtau); return true; }
            // exact global 8th-best via destructive merge of list copies
            float cd2[KNN]; int ci2[KNN];
#pragma unroll
            for (int q = 0; q < KNN; ++q) { cd2[q] = bd[q]; ci2[q] = bi[q]; }
            float d8 = INFINITY;
#pragma unroll
            for (int k = 0; k < KNN; ++k) {
                float dw = cd2[0];
                int   iw = ci2[0];
#pragma unroll
                for (int s = 1; s < 64; s <<= 1) {
                    const float od = __shfl_xor(dw, s, 64);
                    const int   oi = __shfl_xor(iw, s, 64);
                    if (od < dw || (od == dw && oi < iw)) { dw = od; iw = oi; }
                }
                if (cd2[0] == dw && ci2[0] == iw) {
#pragma unroll
                    for (int q = 0; q < KNN - 1; ++q) { cd2[q] = cd2[q + 1]; ci2[q] = ci2[q + 1]; }
                    cd2[KNN - 1] = INFINITY; ci2[KNN - 1] = 0x7fffffff;
                }
                d8 = dw;
            }
            if (d8 < need) { tau = fminf(tau, d8); return true; }
            tau = fminf(tau, d8);
        }
        tau = fminf(tau, wtau);
        return false;
    };

    // ---- Phase A: 5x5x5 window, compile-time divisors ----
#pragma unroll
    for (int it = 0; it < 2; ++it) {
        const int t0 = lane + it * 64;
        if (t0 < 125) {
            const int dz = t0 / 25 - 2;
            const int dy = (t0 / 5) % 5 - 2;
            const int dx = t0 % 5 - 2;
            const int ccx = cx + dx, ccy = cy + dy, ccz = cz + dz;
            if ((unsigned)ccx < GRID_R && (unsigned)ccy < GRID_R && (unsigned)ccz < GRID_R)
                scan_cell(ccx, ccy, ccz);
        }
    }
    bool done = term_check(2);

    // ---- generic ring fallback (rare: low-density tail targets) ----
    if (!done) {
        for (int r = 3; r <= GRID_R; ++r) {
            const int W = 2 * r + 1, W2 = W * W, vol = W2 * W;
            for (int t0 = lane; t0 < vol; t0 += 64) {
                int dz = t0 / W2;
                int rem = t0 - dz * W2;
                int dy = rem / W;
                int dx = rem - dy * W;
                dx -= r; dy -= r; dz -= r;
                const int ax = dx < 0 ? -dx : dx;
                const int ay = dy < 0 ? -dy : dy;
                const int az = dz < 0 ? -dz : dz;
                if (max(ax, max(ay, az)) != r) continue;
                const int ccx = cx + dx, ccy = cy + dy, ccz = cz + dz;
                if ((unsigned)ccx >= GRID_R || (unsigned)ccy >= GRID_R || (unsigned)ccz >= GRID_R)
                    continue;
                scan_cell(ccx, ccy, ccz);
            }
            if (term_check(r)) break;
        }
    }

    // ---- final merge of 64 sorted lists (lex), emit top-8 ----
#pragma unroll
    for (int k = 0; k < KNN; ++k) {
        float dw = bd[0];
        int   iw = bi[0];
#pragma unroll
        for (int s = 1; s < 64; s <<= 1) {
            const float od = __shfl_xor(dw, s, 64);
            const int   oi = __shfl_xor(iw, s, 64);
            if (od < dw || (od == dw && oi < iw)) { dw = od; iw = oi; }
        }
        if (bd[0] == dw && bi[0] == iw) {
#pragma unroll
            for (int q = 0; q < KNN - 1; ++q) { bd[q] = bd[q + 1]; bi[q] = bi[q + 1]; }
            bd[KNN - 1] = INFINITY; bi[KNN - 1] = 0x7fffffff;
        }
        if (lane == 0) idx_out[i * 9 + k] = clamp_idx(iw);
    }
    if (lane == 0) idx_out[i * 9 + 8] = i;
}

__global__ __launch_bounds__(256) void knn_grid_kernel(const void* __restrict__ pos,
                                                       const int* __restrict__ flag,
                                                       const int* __restrict__ cstart,
                                                       const int* __restrict__ ccnt,
                                                       const float4* __restrict__ pts4,
                                                       const int* __restrict__ pid,
                                                       int* __restrict__ idx_out) {
    if (get_dt(flag) == DT_BF16) knn_body<__hip_bfloat16>((const __hip_bfloat16*)pos, cstart, ccnt, pts4, pid, idx_out);
    else                         knn_body<float>((const float*)pos, cstart, ccnt, pts4, pid, idx_out);
}

// ---------------------------------------------------------------------------
// conv1 v3: first layer factored:
//   h1[n] = relu( pos_j@(Wtop+Wbot) - pos_i@Wbot + bA )   (msg GEMM deleted)
// ---------------------------------------------------------------------------
struct Conv1Smem {
    alignas(16) float wB[32 * 64];
    alignas(16) float h1s[4][9 * 32];
    alignas(16) float wsum[3 * 32];
    alignas(16) float wbot[3 * 32];
    alignas(16) float posn[4][9][3];
    float bA[32];
    float bB[64];
};

template <typename T>
__device__ void conv1_body(const T* __restrict__ pos, const int* __restrict__ idx,
                           const T* __restrict__ W1a, const T* __restrict__ b1a,
                           const T* __restrict__ W1b, const T* __restrict__ b1b,
                           float* __restrict__ x1, Conv1Smem& s) {
    const int tid = threadIdx.x;
    for (int e = tid; e < 96; e += 256) {
        const float bot = ldf(W1a, 96 + e);
        s.wsum[e] = ldf(W1a, e) + bot;
        s.wbot[e] = bot;
    }
    if (tid < 32) s.bA[tid] = ldf(b1a, tid);
    for (int e = tid; e < 2048; e += 256) s.wB[e] = ldf(W1b, e);
    if (tid < 64) s.bB[tid] = ldf(b1b, tid);

    const int tl   = tid >> 6;
    const int lane = tid & 63;
    const int i    = blockIdx.x * 4 + tl;

    if (lane < 27) {
        const int n = lane / 3, c = lane % 3;
        const int j = clamp_idx(idx[i * 9 + n]);
        s.posn[tl][n][c] = ldf(pos, 3 * j + c);
    }
    const float pi0 = ldf(pos, 3 * i + 0);
    const float pi1 = ldf(pos, 3 * i + 1);
    const float pi2 = ldf(pos, 3 * i + 2);
    __syncthreads();

    for (int e = lane; e < 288; e += 64) {
        const int n = e >> 5, k = e & 31;
        float b = fmaf(pi0, s.wbot[k], fmaf(pi1, s.wbot[32 + k], pi2 * s.wbot[64 + k]));
        float v = s.bA[k] - b;
        v = fmaf(s.posn[tl][n][0], s.wsum[k], v);
        v = fmaf(s.posn[tl][n][1], s.wsum[32 + k], v);
        v = fmaf(s.posn[tl][n][2], s.wsum[64 + k], v);
        s.h1s[tl][n * 32 + k] = fmaxf(v, 0.0f);
    }
    __syncthreads();

    float wcol[32];
#pragma unroll
    for (int k = 0; k < 32; ++k) wcol[k] = s.wB[k * 64 + lane];

    float acc = -INFINITY;
    for (int n = 0; n < 9; ++n) {
        float v = s.bB[lane];
#pragma unroll
        for (int k = 0; k < 32; ++k) v = fmaf(s.h1s[tl][n * 32 + k], wcol[k], v);
        acc = fmaxf(acc, v);
    }
    x1[i * 64 + lane] = fmaxf(acc, 0.0f);   // outer relu (x for conv2)
}

__global__ __launch_bounds__(256) void conv1_kernel(const void* __restrict__ pos,
                                                    const int* __restrict__ flag,
                                                    const int* __restrict__ idx,
                                                    const void* __restrict__ W1a,
                                                    const void* __restrict__ b1a,
                                                    const void* __restrict__ W1b,
                                                    const void* __restrict__ b1b,
                                                    float* __restrict__ x1) {
    __shared__ Conv1Smem s;
    if (get_dt(flag) == DT_BF16)
        conv1_body<__hip_bfloat16>((const __hip_bfloat16*)pos, idx,
            (const __hip_bfloat16*)W1a, (const __hip_bfloat16*)b1a,
            (const __hip_bfloat16*)W1b, (const __hip_bfloat16*)b1b, x1, s);
    else
        conv1_body<float>((const float*)pos, idx, (const float*)W1a, (const float*)b1a,
            (const float*)W1b, (const float*)b1b, x1, s);
}

// ---------------------------------------------------------------------------
// zw: per-point precompute for conv2's first layer (in-place over x1):
//   zw[j][k] = b2a[k] + sum_c<64 x1[j][c]*W2a[c][k] + sum_c<3 pos_j[c]*W2a[64+c][k]
// Removes the 9x-redundant per-edge GEMM from conv2 entirely.
// ---------------------------------------------------------------------------
struct ZwSmem {
    alignas(16) float wA[67 * 64];
    alignas(16) float xrT[4][68][4];   // [wave][c][point], c rows 0..66 used
    float bA[64];
};

template <typename T>
__device__ void zw_body(const T* __restrict__ pos, const T* __restrict__ W2a,
                        const T* __restrict__ b2a, float* __restrict__ x1, ZwSmem& s) {
    const int tid  = threadIdx.x;
    const int wv   = tid >> 6;
    const int lane = tid & 63;
    const int j0   = blockIdx.x * 16 + wv * 4;

    for (int e = tid; e < 4288; e += 256) s.wA[e] = ldf(W2a, e);
    if (tid < 64) s.bA[tid] = ldf(b2a, tid);

    // stage 4 points transposed: xrT[c][p]
#pragma unroll
    for (int p = 0; p < 4; ++p)
        s.xrT[wv][lane][p] = x1[(j0 + p) * 64 + lane];
    if (lane < 12) {
        const int p = lane / 3, c = lane % 3;
        s.xrT[wv][64 + c][p] = ldf(pos, 3 * (j0 + p) + c);
    }
    __syncthreads();

    float a0 = s.bA[lane], a1 = a0, a2 = a0, a3 = a0;
    for (int c = 0; c < 67; ++c) {
        const float w = s.wA[c * 64 + lane];
        const float4 xv = *(const float4*)&s.xrT[wv][c][0];
        a0 = fmaf(xv.x, w, a0);
        a1 = fmaf(xv.y, w, a1);
        a2 = fmaf(xv.z, w, a2);
        a3 = fmaf(xv.w, w, a3);
    }
    // in-place: each row read only by this wave, staged above
    x1[(j0 + 0) * 64 + lane] = a0;
    x1[(j0 + 1) * 64 + lane] = a1;
    x1[(j0 + 2) * 64 + lane] = a2;
    x1[(j0 + 3) * 64 + lane] = a3;
}

__global__ __launch_bounds__(256) void zw_kernel(const void* __restrict__ pos,
                                                 const int* __restrict__ flag,
                                                 const void* __restrict__ W2a,
                                                 const void* __restrict__ b2a,
                                                 float* __restrict__ x1) {
    __shared__ ZwSmem s;
    if (get_dt(flag) == DT_BF16)
        zw_body<__hip_bfloat16>((const __hip_bfloat16*)pos, (const __hip_bfloat16*)W2a,
                                (const __hip_bfloat16*)b2a, x1, s);
    else
        zw_body<float>((const float*)pos, (const float*)W2a, (const float*)b2a, x1, s);
}

// ---------------------------------------------------------------------------
// conv2+head v3: h1[n] = relu(zw[j_n] - pos_i@W2a_bot). No wAT LDS (the round-2
// bank-conflict source), no msg staging, no per-edge 67-K GEMM. wB phase and
// head unchanged.
// ---------------------------------------------------------------------------
struct Conv2Smem {
    alignas(16) float h1s[4][9 * 64];
    alignas(16) float row[4][128];
    alignas(16) float wbot[3 * 64];
    alignas(16) float wc[640];
    float bcs[5];
    float sv[4][5];
    int   nb[4][9];
};

template <typename T>
__device__ void conv2_body(const T* __restrict__ pos, const int* __restrict__ idx,
                           const float* __restrict__ zw,
                           const T* __restrict__ W2a, const T* __restrict__ W2b,
                           const T* __restrict__ b2b, const T* __restrict__ Wc,
                           const T* __restrict__ bc, T* __restrict__ out, Conv2Smem& s) {
    const int tid  = threadIdx.x;
    const int l    = tid & 127;
    const int half = tid >> 7;

    float wcol[64];
#pragma unroll
    for (int k = 0; k < 64; ++k) wcol[k] = ldf(W2b, k * 128 + l);
    const float bBl = ldf(b2b, l);

    for (int e = tid; e < 192; e += 256) s.wbot[e] = ldf(W2a, 4096 + e);  // rows 64..66
    for (int e = tid; e < 640; e += 256) s.wc[e] = ldf(Wc, e);
    if (tid < 5) s.bcs[tid] = ldf(bc, tid);

    const int tl   = tid >> 6;
    const int lane = tid & 63;
    const int i    = blockIdx.x * 4 + tl;

    if (lane < 9) s.nb[tl][lane] = clamp_idx(idx[i * 9 + lane]);
    const float pi0 = ldf(pos, 3 * i + 0);
    const float pi1 = ldf(pos, 3 * i + 1);
    const float pi2 = ldf(pos, 3 * i + 2);
    __syncthreads();

    // h1 = relu(zw[j] - vi): 9 coalesced row-gathers + subtract
    {
        const float vi = fmaf(pi0, s.wbot[lane], fmaf(pi1, s.wbot[64 + lane], pi2 * s.wbot[128 + lane]));
#pragma unroll
        for (int n = 0; n < 9; ++n) {
            const int j = s.nb[tl][n];
            s.h1s[tl][n * 64 + lane] = fmaxf(zw[j * 64 + lane] - vi, 0.0f);
        }
    }
    __syncthreads();

    // wB phase: thread (half, l) does 2 targets
#pragma unroll
    for (int tt = 0; tt < 2; ++tt) {
        const int tgt = half * 2 + tt;
        float acc = -INFINITY;
        for (int n = 0; n < 9; ++n) {
            float v = bBl;
            for (int k = 0; k < 64; k += 4) {
                const float4 hv = *(const float4*)&s.h1s[tgt][n * 64 + k];
                v = fmaf(hv.x, wcol[k + 0], v);
                v = fmaf(hv.y, wcol[k + 1], v);
                v = fmaf(hv.z, wcol[k + 2], v);
                v = fmaf(hv.w, wcol[k + 3], v);
            }
            acc = fmaxf(acc, v);
        }
        s.row[tgt][l] = fmaxf(acc, 0.0f);
    }
    __syncthreads();

    // head + log_softmax
    if (tid < 20) {
        const int tgt = tid / 5, o = tid % 5;
        float v = s.bcs[o];
        for (int k = 0; k < 128; ++k) v = fmaf(s.row[tgt][k], s.wc[k * 5 + o], v);
        s.sv[tgt][o] = v;
    }
    __syncthreads();
    if (tid < 20) {
        const int tgt = tid / 5, o = tid % 5;
        float m = s.sv[tgt][0];
#pragma unroll
        for (int q = 1; q < 5; ++q) m = fmaxf(m, s.sv[tgt][q]);
        float sum = 0.0f;
#pragma unroll
        for (int q = 0; q < 5; ++q) sum += expf(s.sv[tgt][q] - m);
        const float lse = m + logf(sum);
        stf(out, (blockIdx.x * 4 + tgt) * 5 + o, s.sv[tgt][o] - lse);
    }
}

__global__ __launch_bounds__(256) void conv2_head_kernel(const void* __restrict__ pos,
                                                         const int* __restrict__ flag,
                                                         const int* __restrict__ idx,
                                                         const float* __restrict__ zw,
                                                         const void* __restrict__ W2a,
                                                         const void* __restrict__ W2b,
                                                         const void* __restrict__ b2b,
                                                         const void* __restrict__ Wc,
                                                         const void* __restrict__ bc,
                                                         void* __restrict__ out) {
    __shared__ Conv2Smem s;
    if (get_dt(flag) == DT_BF16)
        conv2_body<__hip_bfloat16>((const __hip_bfloat16*)pos, idx, zw,
            (const __hip_bfloat16*)W2a, (const __hip_bfloat16*)W2b, (const __hip_bfloat16*)b2b,
            (const __hip_bfloat16*)Wc, (const __hip_bfloat16*)bc, (__hip_bfloat16*)out, s);
    else
        conv2_body<float>((const float*)pos, idx, zw, (const float*)W2a, (const float*)W2b,
            (const float*)b2b, (const float*)Wc, (const float*)bc, (float*)out, s);
}

// ---------------------------------------------------------------------------
extern "C" void kernel_launch(void* const* d_in, const int* in_sizes, int n_in,
                              void* d_out, int out_size, void* d_ws, size_t ws_size,
                              hipStream_t stream) {
    if (ws_size < (size_t)WS_NEEDED) return;

    char* ws = (char*)d_ws;
    int*    flag   = (int*)(ws + WS_FLAG_OFF);
    int*    idx    = (int*)(ws + WS_IDX_OFF);
    float*  x1     = (float*)(ws + WS_X1_OFF);
    int*    cnt    = (int*)(ws + WS_CNT_OFF);
    int*    cstart = (int*)(ws + WS_START_OFF);
    int*    cursor = (int*)(ws + WS_CURSOR_OFF);
    int*    pid    = (int*)(ws + WS_PID_OFF);
    float4* pts4   = (float4*)(ws + WS_PTS_OFF);

    zero_kernel<<<NCELLS / 256, 256, 0, stream>>>(cnt, flag);
    sniff_kernel<<<64, 256, 0, stream>>>((const unsigned short*)d_in[0], flag);
    grid_count_kernel<<<N_PTS / 256, 256, 0, stream>>>(d_in[0], flag, cnt);
    grid_scan_kernel<<<1, 1024, 0, stream>>>(cnt, cstart, cursor);
    grid_scatter_kernel<<<N_PTS / 256, 256, 0, stream>>>(d_in[0], flag, cursor, pts4, pid);
    knn_grid_kernel<<<N_PTS / 4, 256, 0, stream>>>(d_in[0], flag, cstart, cnt, pts4, pid, idx);
    conv1_kernel<<<N_PTS / 4, 256, 0, stream>>>(d_in[0], flag, idx,
        d_in[1], d_in[2], d_in[3], d_in[4], x1);
    zw_kernel<<<N_PTS / 16, 256, 0, stream>>>(d_in[0], flag, d_in[5], d_in[6], x1);
    conv2_head_kernel<<<N_PTS / 4, 256, 0, stream>>>(d_in[0], flag, idx, x1,
        d_in[5], d_in[7], d_in[8], d_in[9], d_in[10], d_out);
}